// Round 13
// baseline (265.047 us; speedup 1.0000x reference)
//
#include <hip/hip_runtime.h>

#define B_ 64
#define N_ 4096
#define D_ 256
#define S_ 8
#define EPSL 1e-5f
#define NCH 16

typedef _Float16 f16x8 __attribute__((ext_vector_type(8)));
typedef _Float16 f16x4 __attribute__((ext_vector_type(4)));
typedef float f32x4 __attribute__((ext_vector_type(4)));

__device__ __forceinline__ void gload_lds16_nt(const void* g, void* l){
    __builtin_amdgcn_global_load_lds(
        (const __attribute__((address_space(1))) unsigned int*)g,
        (__attribute__((address_space(3))) unsigned int*)l, 16, 0, 2);
}

// ============ swizzled f16 A-tile helpers ============
__device__ __forceinline__ void a16_st4(_Float16* a, int row, int col, float4 v){
    int byte = row*512 + ((col*2) ^ ((row&7)<<4));
    f16x4 h; h[0]=(_Float16)v.x; h[1]=(_Float16)v.y; h[2]=(_Float16)v.z; h[3]=(_Float16)v.w;
    *(f16x4*)((char*)a + byte) = h;
}
__device__ __forceinline__ void a16_st2(_Float16* a, int row, int col, _Float16 v){
    int byte = row*512 + ((col*2) ^ ((row&7)<<4));
    *(_Float16*)((char*)a + byte) = v;
}
__device__ __forceinline__ f16x8 a16_ld8(const _Float16* a, int row, int col){
    int byte = row*512 + ((col*2) ^ ((row&7)<<4));
    return *(const f16x8*)((const char*)a + byte);
}
__device__ __forceinline__ f16x8 wfrag_ld(const _Float16* __restrict__ Wf,
        int tt, int ks, int l){
    return *(const f16x8*)(Wf + ((long)tt*4096 + (ks*64 + l)*8));
}

// ---------------- LN(x) -> xn fp16: 2 rows/wave, 16B stores ----------------
__global__ __launch_bounds__(256) void k_ln_x(const float* __restrict__ x,
        const float* __restrict__ g, const float* __restrict__ be,
        _Float16* __restrict__ xn) {
    int w = threadIdx.x >> 6, l = threadIdx.x & 63;
    int half = l >> 5, li = l & 31;
    long row = (long)blockIdx.x * 8 + w*2 + half;
    const float* xr = x + row * D_ + li * 8;
    float4 a = *(const float4*)(xr);
    float4 b = *(const float4*)(xr + 4);
    float s = a.x+a.y+a.z+a.w + b.x+b.y+b.z+b.w;
    float q = a.x*a.x+a.y*a.y+a.z*a.z+a.w*a.w + b.x*b.x+b.y*b.y+b.z*b.z+b.w*b.w;
    #pragma unroll
    for (int m = 1; m < 32; m <<= 1) { s += __shfl_xor(s, m); q += __shfl_xor(q, m); }
    float mean = s * (1.0f/D_);
    float inv = rsqrtf(q * (1.0f/D_) - mean*mean + EPSL);
    float4 gv0 = *(const float4*)(g + li*8);
    float4 gv1 = *(const float4*)(g + li*8 + 4);
    float4 bb0 = *(const float4*)(be + li*8);
    float4 bb1 = *(const float4*)(be + li*8 + 4);
    f16x8 o;
    o[0]=(_Float16)((a.x-mean)*inv*gv0.x+bb0.x);
    o[1]=(_Float16)((a.y-mean)*inv*gv0.y+bb0.y);
    o[2]=(_Float16)((a.z-mean)*inv*gv0.z+bb0.z);
    o[3]=(_Float16)((a.w-mean)*inv*gv0.w+bb0.w);
    o[4]=(_Float16)((b.x-mean)*inv*gv1.x+bb1.x);
    o[5]=(_Float16)((b.y-mean)*inv*gv1.y+bb1.y);
    o[6]=(_Float16)((b.z-mean)*inv*gv1.z+bb1.z);
    o[7]=(_Float16)((b.w-mean)*inv*gv1.w+bb1.w);
    *(f16x8*)(xn + row * D_ + li*8) = o;
}

// ---------------- merged weight prep: [0,256)=composites, [256,1536)=repack ----
__global__ __launch_bounds__(256) void k_wpre(const float* __restrict__ Whh,
        const float* __restrict__ W1, const float* __restrict__ W2,
        _Float16* __restrict__ Whhf, _Float16* __restrict__ W1f,
        _Float16* __restrict__ W2f,
        const float* __restrict__ Wih, const float* __restrict__ Wv,
        const float* __restrict__ Wq, const float* __restrict__ Wk,
        const float* __restrict__ bih, const float* __restrict__ bv,
        const float* __restrict__ bq, _Float16* __restrict__ Wcf,
        _Float16* __restrict__ Wqkf, float* __restrict__ bc,
        float* __restrict__ cq) {
    __shared__ float a4[4][256];
    int r = blockIdx.x, t = threadIdx.x;
    int w = t>>6, l = t&63;
    if (r >= 256){
        int rr = r - 256;
        const float* src; _Float16* dst; int row;
        if (rr < 768){ src = Whh; dst = Whhf; row = rr; }
        else if (rr < 1024){ src = W1; dst = W1f; row = rr - 768; }
        else { src = W2; dst = W2f; row = rr - 1024; }
        float v = src[(long)row*256 + t];
        long di = (long)((((row>>4)*8 + (t>>5))*64 + ((t>>3)&3)*16 + (row&15)))*8 + (t&7);
        dst[di] = (_Float16)v;
        return;
    }
    bool isC = (r < 192);
    if (isC){
        #pragma unroll
        for (int k=0;k<4;k++) a4[k][t] = Wih[(long)(r*4+k)*256 + t];
    } else {
        int dbase = (r-192)*4;
        #pragma unroll
        for (int k=0;k<4;k++) a4[k][t] = Wk[(long)t*256 + dbase + k];
    }
    __syncthreads();
    float ac[4] = {0.f,0.f,0.f,0.f};
    const float* Bm = isC ? Wv : Wq;
    for (int e=0;e<256;e++){
        float bvv = Bm[(long)e*256 + t];
        ac[0] += a4[0][e]*bvv; ac[1] += a4[1][e]*bvv;
        ac[2] += a4[2][e]*bvv; ac[3] += a4[3][e]*bvv;
    }
    _Float16* dst = isC ? Wcf : Wqkf;
    int rb = isC ? r*4 : (r-192)*4;
    #pragma unroll
    for (int k=0;k<4;k++){
        int row = rb + k;
        long di = (long)((((row>>4)*8 + (t>>5))*64 + ((t>>3)&3)*16 + (row&15)))*8 + (t&7);
        dst[di] = (_Float16)ac[k];
    }
    if (w < 4){
        const float* bvec = isC ? bv : bq;
        float p = 0.f;
        #pragma unroll
        for (int q=0;q<4;q++) p += a4[w][l + q*64] * bvec[l + q*64];
        #pragma unroll
        for (int m=1;m<64;m<<=1) p += __shfl_xor(p, m);
        if (l==0){
            if (isC) bc[r*4 + w] = p + bih[r*4 + w];
            else     cq[(r-192)*4 + w] = p;
        }
    }
}

// ---- 8-wave tail MFMA helpers ----
template<int NT, int OS>
__device__ __forceinline__ void mm_stage_f(const _Float16* a16,
        const _Float16* __restrict__ Wf, float* outl, int w, int l){
    int lr = l&15, lh = l>>4;
    f16x8 A[8];
    #pragma unroll
    for (int ks=0;ks<8;ks++) A[ks] = a16_ld8(a16, lr, lh*8 + ks*32);
    #pragma unroll
    for (int tile=0; tile<NT; ++tile){
        int tt = w*NT + tile;
        f32x4 acc = {0.f,0.f,0.f,0.f};
        #pragma unroll
        for (int ks=0;ks<8;ks++)
            acc = __builtin_amdgcn_mfma_f32_16x16x32_f16(A[ks], wfrag_ld(Wf,tt,ks,l), acc, 0,0,0);
        if (lh < 2){
            #pragma unroll
            for (int r=0;r<4;r++) outl[(lh*4+r)*OS + tt*16 + lr] = acc[r];
        }
    }
}

__device__ __forceinline__ void mm_gates_f(const _Float16* au, const _Float16* ah,
        const _Float16* __restrict__ Wcf, const _Float16* __restrict__ Whf,
        float* g1, float* g2, int w, int l){
    int lr = l&15, lh = l>>4;
    f16x8 Au[8], Ah[8];
    #pragma unroll
    for (int ks=0;ks<8;ks++){ Au[ks] = a16_ld8(au, lr, lh*8+ks*32);
                              Ah[ks] = a16_ld8(ah, lr, lh*8+ks*32); }
    #pragma unroll
    for (int tile=0; tile<6; ++tile){
        int tt = w*6 + tile;
        f32x4 a1 = {0.f,0.f,0.f,0.f}, a2 = {0.f,0.f,0.f,0.f};
        #pragma unroll
        for (int ks=0;ks<8;ks++)
            a1 = __builtin_amdgcn_mfma_f32_16x16x32_f16(Au[ks], wfrag_ld(Wcf,tt,ks,l), a1, 0,0,0);
        #pragma unroll
        for (int ks=0;ks<8;ks++)
            a2 = __builtin_amdgcn_mfma_f32_16x16x32_f16(Ah[ks], wfrag_ld(Whf,tt,ks,l), a2, 0,0,0);
        if (lh < 2){
            #pragma unroll
            for (int r=0;r<4;r++){
                int s = lh*4+r;
                g1[s*768 + tt*16 + lr] = a1[r];
                g2[s*768 + tt*16 + lr] = a2[r];
            }
        }
    }
}

// ---------------- init: slots + LN_sl -> qh via Wqk ----------------
__global__ __launch_bounds__(512) void k_init(const float* __restrict__ noise,
        const float* __restrict__ mu, const float* __restrict__ sg,
        const float* __restrict__ g_sl, const float* __restrict__ be_sl,
        const _Float16* __restrict__ Wqkf, const float* __restrict__ cq,
        float* __restrict__ slots, _Float16* __restrict__ qh16) {
    __shared__ __align__(16) _Float16 a16[16*256];
    __shared__ float g1[8*256];
    int t = threadIdx.x, w = t>>6, l = t&63, b = blockIdx.x;
    int col = l*4;
    float4 nz = *(const float4*)(noise + ((long)b*8+w)*256 + col);
    float4 muv = *(const float4*)(mu + col);
    float4 sgv = *(const float4*)(sg + col);
    float4 sl;
    sl.x = muv.x + __expf(sgv.x)*nz.x; sl.y = muv.y + __expf(sgv.y)*nz.y;
    sl.z = muv.z + __expf(sgv.z)*nz.z; sl.w = muv.w + __expf(sgv.w)*nz.w;
    *(float4*)(slots + ((long)b*8+w)*256 + col) = sl;
    float s1 = sl.x+sl.y+sl.z+sl.w;
    float s2 = sl.x*sl.x+sl.y*sl.y+sl.z*sl.z+sl.w*sl.w;
    #pragma unroll
    for (int m=1;m<64;m<<=1){ s1+=__shfl_xor(s1,m); s2+=__shfl_xor(s2,m); }
    float mean = s1*(1.0f/D_);
    float inv = rsqrtf(s2*(1.0f/D_) - mean*mean + EPSL);
    float4 gv = *(const float4*)(g_sl + col);
    float4 bb = *(const float4*)(be_sl + col);
    float4 sn;
    sn.x=(sl.x-mean)*inv*gv.x+bb.x; sn.y=(sl.y-mean)*inv*gv.y+bb.y;
    sn.z=(sl.z-mean)*inv*gv.z+bb.z; sn.w=(sl.w-mean)*inv*gv.w+bb.w;
    a16_st4(a16, w, col, sn);
    float4 z = {0.f,0.f,0.f,0.f};
    a16_st4(a16, 8+w, col, z);
    __syncthreads();
    mm_stage_f<2,256>(a16, Wqkf, g1, w, l);
    __syncthreads();
    for (int idx=t; idx<2048; idx+=512){
        int s = idx>>8, d = idx&255;
        qh16[((long)b*16+s)*D_ + d] = (_Float16)(g1[s*256+d] + cq[d]);
        qh16[((long)b*16+8+s)*D_ + d] = (_Float16)0.f;
    }
}

// ---------------- attn: single-buffer, 16 chunks x 64 batches (4 blocks/CU) ------
__global__ __launch_bounds__(256) void k_attn(const _Float16* __restrict__ xn,
        const _Float16* __restrict__ qh16,
        _Float16* __restrict__ pacc, float* __restrict__ ppsum,
        float* __restrict__ pmax) {
    __shared__ __align__(16) char xt_raw[4*8192];    // 1 x 8 KB per wave; reused as accw
    __shared__ __align__(16) float pt_s[4][16][8];
    __shared__ float mw_s[4][8], psw_s[4][8];
    int t = threadIdx.x, w = t>>6, l = t&63, lr = l&15, lh = l>>4;
    int c = blockIdx.x, b = blockIdx.y;   // c: 0..15 -> 256 rows each

    f16x8 A[8];
    const _Float16* qbase = qh16 + ((long)b*16 + lr)*D_ + lh*8;
    #pragma unroll
    for (int ks=0;ks<8;ks++) A[ks] = *(const f16x8*)(qbase + ks*32);
    asm volatile("s_waitcnt vmcnt(0)" ::: "memory");

    char* xw = xt_raw + w*8192;
    const char* xnb = (const char*)(xn + (long)b*N_*D_);
    int rlo = l>>5;
    int cb  = (l&31)*16;

    {   int n0 = c*256 + w*16;
        #pragma unroll
        for (int j=0;j<8;j++){
            int row = 2*j + rlo;
            const char* gp = xnb + (long)(n0+row)*512 + (cb ^ ((row&7)<<4));
            gload_lds16_nt(gp, xw + j*1024);
        }
    }

    float m8[8];
    #pragma unroll
    for (int s=0;s<8;s++) m8[s] = -1e30f;
    float acc[8][4] = {};
    float psr[4] = {0.f,0.f,0.f,0.f};
    float (*pt)[8] = pt_s[w];
    int fx = (lr&7)<<4;

    for (int sc=0; sc<4; ++sc){
        asm volatile("s_waitcnt vmcnt(0)" ::: "memory");
        __builtin_amdgcn_sched_barrier(0);

        f32x4 lacc = {0.f,0.f,0.f,0.f};
        #pragma unroll
        for (int ks=0;ks<8;ks++){
            f16x8 Bf = *(const f16x8*)(xw + lr*512 + ((lh*16 + ks*64) ^ fx));
            lacc = __builtin_amdgcn_mfma_f32_16x16x32_f16(A[ks], Bf, lacc, 0,0,0);
        }
        float tm[4];
        #pragma unroll
        for (int r=0;r<4;r++) tm[r] = lacc[r];
        #pragma unroll
        for (int m=1;m<16;m<<=1){
            #pragma unroll
            for (int r=0;r<4;r++) tm[r] = fmaxf(tm[r], __shfl_xor(tm[r], m));
        }
        float mN[8];
        #pragma unroll
        for (int r=0;r<4;r++){ mN[r] = __shfl(tm[r], lr); mN[4+r] = __shfl(tm[r], 16+lr); }
        float sc8[8];
        #pragma unroll
        for (int s=0;s<8;s++){
            float mn = fmaxf(m8[s], mN[s]);
            sc8[s] = __expf(m8[s] - mn);
            m8[s] = mn;
        }
        #pragma unroll
        for (int s=0;s<8;s++){
            acc[s][0]*=sc8[s]; acc[s][1]*=sc8[s]; acc[s][2]*=sc8[s]; acc[s][3]*=sc8[s];
        }
        if (lh < 2){
            float4 pv;
            #pragma unroll
            for (int r=0;r<4;r++){
                int s = lh*4+r;
                float p = __expf(lacc[r] - m8[s]);
                psr[r] = psr[r]*sc8[s] + p;
                ((float*)&pv)[r] = p;
            }
            *(float4*)&pt[lr][lh*4] = pv;
        }
        #pragma unroll 4
        for (int i=0;i<16;i++){
            float4 p0 = *(const float4*)&pt[i][0];
            float4 p1 = *(const float4*)&pt[i][4];
            f16x4 xv = *(const f16x4*)(xw + i*512 + ((l*8) ^ ((i&7)<<4)));
            float x0=(float)xv[0], x1=(float)xv[1], x2=(float)xv[2], x3=(float)xv[3];
            acc[0][0]+=p0.x*x0; acc[0][1]+=p0.x*x1; acc[0][2]+=p0.x*x2; acc[0][3]+=p0.x*x3;
            acc[1][0]+=p0.y*x0; acc[1][1]+=p0.y*x1; acc[1][2]+=p0.y*x2; acc[1][3]+=p0.y*x3;
            acc[2][0]+=p0.z*x0; acc[2][1]+=p0.z*x1; acc[2][2]+=p0.z*x2; acc[2][3]+=p0.z*x3;
            acc[3][0]+=p0.w*x0; acc[3][1]+=p0.w*x1; acc[3][2]+=p0.w*x2; acc[3][3]+=p0.w*x3;
            acc[4][0]+=p1.x*x0; acc[4][1]+=p1.x*x1; acc[4][2]+=p1.x*x2; acc[4][3]+=p1.x*x3;
            acc[5][0]+=p1.y*x0; acc[5][1]+=p1.y*x1; acc[5][2]+=p1.y*x2; acc[5][3]+=p1.y*x3;
            acc[6][0]+=p1.z*x0; acc[6][1]+=p1.z*x1; acc[6][2]+=p1.z*x2; acc[6][3]+=p1.z*x3;
            acc[7][0]+=p1.w*x0; acc[7][1]+=p1.w*x1; acc[7][2]+=p1.w*x2; acc[7][3]+=p1.w*x3;
        }
        if (sc < 3){
            asm volatile("s_waitcnt lgkmcnt(0)" ::: "memory");
            __builtin_amdgcn_sched_barrier(0);
            int n0n = c*256 + (sc+1)*64 + w*16;
            #pragma unroll
            for (int j=0;j<8;j++){
                int row = 2*j + rlo;
                const char* gp = xnb + (long)(n0n+row)*512 + (cb ^ ((row&7)<<4));
                gload_lds16_nt(gp, xw + j*1024);
            }
        }
    }
    #pragma unroll
    for (int m=1;m<16;m<<=1){
        #pragma unroll
        for (int r=0;r<4;r++) psr[r] += __shfl_xor(psr[r], m);
    }
    if (l == 0){
        #pragma unroll
        for (int s=0;s<8;s++) mw_s[w][s] = m8[s];
        #pragma unroll
        for (int r=0;r<4;r++) psw_s[w][r] = psr[r];
    }
    if (l == 16){
        #pragma unroll
        for (int r=0;r<4;r++) psw_s[w][4+r] = psr[r];
    }
    __syncthreads();
    float M8[8];
    #pragma unroll
    for (int s=0;s<8;s++)
        M8[s] = fmaxf(fmaxf(mw_s[0][s],mw_s[1][s]), fmaxf(mw_s[2][s],mw_s[3][s]));
    float* accw = (float*)xt_raw;   // [4 waves][8 s][256 d] = 32 KB
    #pragma unroll
    for (int s=0;s<8;s++){
        float wsc = __expf(m8[s] - M8[s]);
        float4 v;
        v.x=acc[s][0]*wsc; v.y=acc[s][1]*wsc; v.z=acc[s][2]*wsc; v.w=acc[s][3]*wsc;
        *(float4*)&accw[((w*8+s)<<8) + l*4] = v;
    }
    __syncthreads();
    for (int pair=t; pair<2048; pair+=256){
        int s = pair>>8, d = pair&255;
        float v = accw[(s<<8)+d] + accw[((8+s)<<8)+d] + accw[((16+s)<<8)+d] + accw[((24+s)<<8)+d];
        pacc[(((long)b*NCH + c)*8 + s)*D_ + d] = (_Float16)v;
    }
    if (t < 8){
        float ps = 0.f;
        #pragma unroll
        for (int w2=0;w2<4;w2++) ps += __expf(mw_s[w2][t]-M8[t]) * psw_s[w2][t];
        ppsum[((long)b*NCH+c)*8 + t] = ps;
        pmax [((long)b*NCH+c)*8 + t] = M8[t];
    }
}

// ---------------- tail ----------------
__global__ __launch_bounds__(512) void k_tail(
    const _Float16* __restrict__ pacc, const float* __restrict__ ppsum,
    const float* __restrict__ pmax, const float* __restrict__ slots,
    const _Float16* __restrict__ Wcf, const float* __restrict__ bc,
    const _Float16* __restrict__ Whhf, const float* __restrict__ bhh,
    const _Float16* __restrict__ W1f, const float* __restrict__ b1,
    const _Float16* __restrict__ W2f, const float* __restrict__ b2,
    const float* __restrict__ gm, const float* __restrict__ bem,
    const float* __restrict__ g_sl, const float* __restrict__ be_sl,
    const _Float16* __restrict__ Wqkf, const float* __restrict__ cq,
    float* __restrict__ out, _Float16* __restrict__ qh16, int last) {
    int t = threadIdx.x, w = t>>6, l = t&63;
    int b = blockIdx.x;
    __shared__ float hb[8][256], hn[8][256];
    __shared__ float g1[8*768], g2[8*768];
    __shared__ __align__(16) _Float16 a16a[16*256], a16b[16*256];
    __shared__ float pss[8];
    __shared__ float wcs[8][NCH];

    if (t < 8){
        float pm[NCH]; float M = -1e30f;
        #pragma unroll
        for (int c=0;c<NCH;c++){ pm[c] = pmax[((long)b*NCH+c)*8+t]; M = fmaxf(M, pm[c]); }
        float ps = 0.f;
        #pragma unroll
        for (int c=0;c<NCH;c++){
            float wc = __expf(pm[c]-M);
            wcs[t][c] = wc;
            ps += wc*ppsum[((long)b*NCH+c)*8+t];
        }
        pss[t] = ps;
    }
    __syncthreads();
    for (int idx=t; idx<2048; idx+=512){
        int s = idx>>8, d = idx&255;
        float v = 0.f;
        #pragma unroll
        for (int c=0;c<NCH;c++) v += wcs[s][c]*(float)pacc[(((long)b*NCH+c)*8+s)*D_ + d];
        float axv = v / pss[s];
        float hbv = slots[((long)b*8+s)*D_ + d];
        hb[s][d] = hbv;
        a16_st2(a16a, s, d, (_Float16)axv);
        a16_st2(a16b, s, d, (_Float16)hbv);
    }
    {   float4 z = {0.f,0.f,0.f,0.f};
        a16_st4(a16a, 8+w, l*4, z);
        a16_st4(a16b, 8+w, l*4, z);
    }
    __syncthreads();
    mm_gates_f(a16a, a16b, Wcf, Whhf, g1, g2, w, l);
    __syncthreads();
    {
        int d0 = l*4;
        float hn4[4];
        #pragma unroll
        for (int i=0;i<4;i++){
            int d = d0+i;
            float r = 1.f/(1.f+__expf(-(g1[w*768+d]     + bc[d]     + g2[w*768+d]     + bhh[d])));
            float z = 1.f/(1.f+__expf(-(g1[w*768+256+d] + bc[256+d] + g2[w*768+256+d] + bhh[256+d])));
            float gg = g1[w*768+512+d] + bc[512+d] + r*(g2[w*768+512+d] + bhh[512+d]);
            float e2 = __expf(2.f*gg);
            float nn = 1.f - 2.f/(e2+1.f);
            hn4[i] = (1.f-z)*nn + z*hb[w][d];
            hn[w][d] = hn4[i];
        }
        float s1 = hn4[0]+hn4[1]+hn4[2]+hn4[3];
        float s2 = hn4[0]*hn4[0]+hn4[1]*hn4[1]+hn4[2]*hn4[2]+hn4[3]*hn4[3];
        #pragma unroll
        for (int m=1;m<64;m<<=1){ s1+=__shfl_xor(s1,m); s2+=__shfl_xor(s2,m); }
        float mean = s1*(1.0f/D_);
        float inv = rsqrtf(s2*(1.0f/D_) - mean*mean + EPSL);
        float4 gv = *(const float4*)(gm + d0);
        float4 bb = *(const float4*)(bem + d0);
        float4 v;
        v.x=(hn4[0]-mean)*inv*gv.x+bb.x; v.y=(hn4[1]-mean)*inv*gv.y+bb.y;
        v.z=(hn4[2]-mean)*inv*gv.z+bb.z; v.w=(hn4[3]-mean)*inv*gv.w+bb.w;
        a16_st4(a16a, w, d0, v);
    }
    __syncthreads();
    mm_stage_f<2,256>(a16a, W1f, g1, w, l);
    __syncthreads();
    {
        int d0 = l*4;
        float4 v = *(const float4*)&g1[w*256+d0];
        float4 bb = *(const float4*)(b1 + d0);
        v.x=fmaxf(v.x+bb.x,0.f); v.y=fmaxf(v.y+bb.y,0.f);
        v.z=fmaxf(v.z+bb.z,0.f); v.w=fmaxf(v.w+bb.w,0.f);
        a16_st4(a16b, w, d0, v);
    }
    __syncthreads();
    mm_stage_f<2,256>(a16b, W2f, g2, w, l);
    __syncthreads();
    {
        int d0 = l*4;
        float4 bb = *(const float4*)(b2 + d0);
        float4 o4;
        o4.x = hn[w][d0]   + g2[w*256+d0]   + bb.x;
        o4.y = hn[w][d0+1] + g2[w*256+d0+1] + bb.y;
        o4.z = hn[w][d0+2] + g2[w*256+d0+2] + bb.z;
        o4.w = hn[w][d0+3] + g2[w*256+d0+3] + bb.w;
        *(float4*)(out + ((long)b*8+w)*D_ + d0) = o4;
        if (!last){
            float s1 = o4.x+o4.y+o4.z+o4.w;
            float s2 = o4.x*o4.x+o4.y*o4.y+o4.z*o4.z+o4.w*o4.w;
            #pragma unroll
            for (int m=1;m<64;m<<=1){ s1+=__shfl_xor(s1,m); s2+=__shfl_xor(s2,m); }
            float mean = s1*(1.0f/D_);
            float inv = rsqrtf(s2*(1.0f/D_) - mean*mean + EPSL);
            float4 gv = *(const float4*)(g_sl + d0);
            float4 be = *(const float4*)(be_sl + d0);
            float4 v;
            v.x=(o4.x-mean)*inv*gv.x+be.x; v.y=(o4.y-mean)*inv*gv.y+be.y;
            v.z=(o4.z-mean)*inv*gv.z+be.z; v.w=(o4.w-mean)*inv*gv.w+be.w;
            a16_st4(a16a, w, d0, v);
        }
    }
    if (last) return;
    __syncthreads();
    mm_stage_f<2,256>(a16a, Wqkf, g1, w, l);
    __syncthreads();
    for (int idx=t; idx<2048; idx+=512){
        int s = idx>>8, d = idx&255;
        qh16[((long)b*16+s)*D_ + d] = (_Float16)(g1[s*256+d] + cq[d]);
    }
}

extern "C" void kernel_launch(void* const* d_in, const int* in_sizes, int n_in,
                              void* d_out, int out_size, void* d_ws, size_t ws_size,
                              hipStream_t stream) {
    const float* x     = (const float*)d_in[0];
    const float* noise = (const float*)d_in[1];
    const float* mu    = (const float*)d_in[2];
    const float* sg    = (const float*)d_in[3];
    const float* Wq    = (const float*)d_in[4];
    const float* bq    = (const float*)d_in[5];
    const float* Wk    = (const float*)d_in[6];
    // d_in[7] = bk: softmax-invariant, unused
    const float* Wv    = (const float*)d_in[8];
    const float* bv    = (const float*)d_in[9];
    const float* Wih   = (const float*)d_in[10];
    const float* bih   = (const float*)d_in[11];
    const float* Whh   = (const float*)d_in[12];
    const float* bhh   = (const float*)d_in[13];
    const float* W1    = (const float*)d_in[14];
    const float* b1    = (const float*)d_in[15];
    const float* W2    = (const float*)d_in[16];
    const float* b2    = (const float*)d_in[17];
    const float* g_in  = (const float*)d_in[18];
    const float* be_in = (const float*)d_in[19];
    const float* g_sl  = (const float*)d_in[20];
    const float* be_sl = (const float*)d_in[21];
    const float* g_mlp = (const float*)d_in[22];
    const float* be_mlp= (const float*)d_in[23];

    char* ws = (char*)d_ws;
    _Float16* xn16  = (_Float16*)(ws);                   // 134217728 B
    _Float16* qh16  = (_Float16*)(ws + 134217728);       //    524288 B
    float*    slots = (float*)   (ws + 134742016);       //    524288 B
    _Float16* pacc  = (_Float16*)(ws + 135266304);       //   4194304 B (64*16*8*256 f16)
    float*    ppsum = (float*)   (ws + 139460608);       //     32768 B
    float*    pmax  = (float*)   (ws + 139493376);       //     32768 B
    _Float16* w16f  = (_Float16*)(ws + 139526144);       //   1179648 B
    float*    bc    = (float*)   (ws + 140705792);       //      3072 B
    float*    cq    = (float*)   (ws + 140708864);       //      1024 B

    _Float16* Wcf  = w16f;             // 768x256 frag
    _Float16* Whhf = w16f + 196608;    // 768x256 frag
    _Float16* W1f  = w16f + 393216;    // 256x256 frag
    _Float16* W2f  = w16f + 458752;    // 256x256 frag
    _Float16* Wqkf = w16f + 524288;    // 256x256 frag

    hipLaunchKernelGGL(k_wpre, dim3(1536), dim3(256), 0, stream,
                       Whh, W1, W2, Whhf, W1f, W2f,
                       Wih, Wv, Wq, Wk, bih, bv, bq, Wcf, Wqkf, bc, cq);
    hipLaunchKernelGGL(k_ln_x, dim3(32768), dim3(256), 0, stream, x, g_in, be_in, xn16);
    hipLaunchKernelGGL(k_init, dim3(64), dim3(512), 0, stream,
                       noise, mu, sg, g_sl, be_sl, Wqkf, cq, slots, qh16);
    for (int it = 0; it < 3; it++){
        hipLaunchKernelGGL(k_attn, dim3(NCH,64), dim3(256), 0, stream,
                           xn16, qh16, pacc, ppsum, pmax);
        float* dst = (it==2) ? (float*)d_out : slots;
        hipLaunchKernelGGL(k_tail, dim3(64), dim3(512), 0, stream,
                           pacc, ppsum, pmax, slots,
                           Wcf, bc, Whhf, bhh, W1f, b1, W2f, b2,
                           g_mlp, be_mlp, g_sl, be_sl, Wqkf, cq,
                           dst, qh16, (it==2) ? 1 : 0);
    }
}

// Round 14
// 249.750 us; speedup vs baseline: 1.0612x; 1.0612x over previous
//
#include <hip/hip_runtime.h>

#define B_ 64
#define N_ 4096
#define D_ 256
#define S_ 8
#define EPSL 1e-5f

typedef _Float16 f16x8 __attribute__((ext_vector_type(8)));
typedef _Float16 f16x4 __attribute__((ext_vector_type(4)));
typedef float f32x4 __attribute__((ext_vector_type(4)));

__device__ __forceinline__ void gload_lds16_nt(const void* g, void* l){
    __builtin_amdgcn_global_load_lds(
        (const __attribute__((address_space(1))) unsigned int*)g,
        (__attribute__((address_space(3))) unsigned int*)l, 16, 0, 2);
}

// ============ swizzled f16 A-tile helpers ============
__device__ __forceinline__ void a16_st4(_Float16* a, int row, int col, float4 v){
    int byte = row*512 + ((col*2) ^ ((row&7)<<4));
    f16x4 h; h[0]=(_Float16)v.x; h[1]=(_Float16)v.y; h[2]=(_Float16)v.z; h[3]=(_Float16)v.w;
    *(f16x4*)((char*)a + byte) = h;
}
__device__ __forceinline__ void a16_st2(_Float16* a, int row, int col, _Float16 v){
    int byte = row*512 + ((col*2) ^ ((row&7)<<4));
    *(_Float16*)((char*)a + byte) = v;
}
__device__ __forceinline__ f16x8 a16_ld8(const _Float16* a, int row, int col){
    int byte = row*512 + ((col*2) ^ ((row&7)<<4));
    return *(const f16x8*)((const char*)a + byte);
}
__device__ __forceinline__ f16x8 wfrag_ld(const _Float16* __restrict__ Wf,
        int tt, int ks, int l){
    return *(const f16x8*)(Wf + ((long)tt*4096 + (ks*64 + l)*8));
}

// ---------------- LN(x) -> xn fp16: 2 rows/wave, 16B stores ----------------
__global__ __launch_bounds__(256) void k_ln_x(const float* __restrict__ x,
        const float* __restrict__ g, const float* __restrict__ be,
        _Float16* __restrict__ xn) {
    int w = threadIdx.x >> 6, l = threadIdx.x & 63;
    int half = l >> 5, li = l & 31;
    long row = (long)blockIdx.x * 8 + w*2 + half;
    const float* xr = x + row * D_ + li * 8;
    float4 a = *(const float4*)(xr);
    float4 b = *(const float4*)(xr + 4);
    float s = a.x+a.y+a.z+a.w + b.x+b.y+b.z+b.w;
    float q = a.x*a.x+a.y*a.y+a.z*a.z+a.w*a.w + b.x*b.x+b.y*b.y+b.z*b.z+b.w*b.w;
    #pragma unroll
    for (int m = 1; m < 32; m <<= 1) { s += __shfl_xor(s, m); q += __shfl_xor(q, m); }
    float mean = s * (1.0f/D_);
    float inv = rsqrtf(q * (1.0f/D_) - mean*mean + EPSL);
    float4 gv0 = *(const float4*)(g + li*8);
    float4 gv1 = *(const float4*)(g + li*8 + 4);
    float4 bb0 = *(const float4*)(be + li*8);
    float4 bb1 = *(const float4*)(be + li*8 + 4);
    f16x8 o;
    o[0]=(_Float16)((a.x-mean)*inv*gv0.x+bb0.x);
    o[1]=(_Float16)((a.y-mean)*inv*gv0.y+bb0.y);
    o[2]=(_Float16)((a.z-mean)*inv*gv0.z+bb0.z);
    o[3]=(_Float16)((a.w-mean)*inv*gv0.w+bb0.w);
    o[4]=(_Float16)((b.x-mean)*inv*gv1.x+bb1.x);
    o[5]=(_Float16)((b.y-mean)*inv*gv1.y+bb1.y);
    o[6]=(_Float16)((b.z-mean)*inv*gv1.z+bb1.z);
    o[7]=(_Float16)((b.w-mean)*inv*gv1.w+bb1.w);
    *(f16x8*)(xn + row * D_ + li*8) = o;
}

// ---------------- merged weight prep: [0,256)=composites, [256,1536)=repack ----
__global__ __launch_bounds__(256) void k_wpre(const float* __restrict__ Whh,
        const float* __restrict__ W1, const float* __restrict__ W2,
        _Float16* __restrict__ Whhf, _Float16* __restrict__ W1f,
        _Float16* __restrict__ W2f,
        const float* __restrict__ Wih, const float* __restrict__ Wv,
        const float* __restrict__ Wq, const float* __restrict__ Wk,
        const float* __restrict__ bih, const float* __restrict__ bv,
        const float* __restrict__ bq, _Float16* __restrict__ Wcf,
        _Float16* __restrict__ Wqkf, float* __restrict__ bc,
        float* __restrict__ cq) {
    __shared__ float a4[4][256];
    int r = blockIdx.x, t = threadIdx.x;
    int w = t>>6, l = t&63;
    if (r >= 256){
        int rr = r - 256;
        const float* src; _Float16* dst; int row;
        if (rr < 768){ src = Whh; dst = Whhf; row = rr; }
        else if (rr < 1024){ src = W1; dst = W1f; row = rr - 768; }
        else { src = W2; dst = W2f; row = rr - 1024; }
        float v = src[(long)row*256 + t];
        long di = (long)((((row>>4)*8 + (t>>5))*64 + ((t>>3)&3)*16 + (row&15)))*8 + (t&7);
        dst[di] = (_Float16)v;
        return;
    }
    bool isC = (r < 192);
    if (isC){
        #pragma unroll
        for (int k=0;k<4;k++) a4[k][t] = Wih[(long)(r*4+k)*256 + t];
    } else {
        int dbase = (r-192)*4;
        #pragma unroll
        for (int k=0;k<4;k++) a4[k][t] = Wk[(long)t*256 + dbase + k];
    }
    __syncthreads();
    float ac[4] = {0.f,0.f,0.f,0.f};
    const float* Bm = isC ? Wv : Wq;
    for (int e=0;e<256;e++){
        float bvv = Bm[(long)e*256 + t];
        ac[0] += a4[0][e]*bvv; ac[1] += a4[1][e]*bvv;
        ac[2] += a4[2][e]*bvv; ac[3] += a4[3][e]*bvv;
    }
    _Float16* dst = isC ? Wcf : Wqkf;
    int rb = isC ? r*4 : (r-192)*4;
    #pragma unroll
    for (int k=0;k<4;k++){
        int row = rb + k;
        long di = (long)((((row>>4)*8 + (t>>5))*64 + ((t>>3)&3)*16 + (row&15)))*8 + (t&7);
        dst[di] = (_Float16)ac[k];
    }
    if (w < 4){
        const float* bvec = isC ? bv : bq;
        float p = 0.f;
        #pragma unroll
        for (int q=0;q<4;q++) p += a4[w][l + q*64] * bvec[l + q*64];
        #pragma unroll
        for (int m=1;m<64;m<<=1) p += __shfl_xor(p, m);
        if (l==0){
            if (isC) bc[r*4 + w] = p + bih[r*4 + w];
            else     cq[(r-192)*4 + w] = p;
        }
    }
}

// ---- 8-wave tail MFMA helpers ----
template<int NT, int OS>
__device__ __forceinline__ void mm_stage_f(const _Float16* a16,
        const _Float16* __restrict__ Wf, float* outl, int w, int l){
    int lr = l&15, lh = l>>4;
    f16x8 A[8];
    #pragma unroll
    for (int ks=0;ks<8;ks++) A[ks] = a16_ld8(a16, lr, lh*8 + ks*32);
    #pragma unroll
    for (int tile=0; tile<NT; ++tile){
        int tt = w*NT + tile;
        f32x4 acc = {0.f,0.f,0.f,0.f};
        #pragma unroll
        for (int ks=0;ks<8;ks++)
            acc = __builtin_amdgcn_mfma_f32_16x16x32_f16(A[ks], wfrag_ld(Wf,tt,ks,l), acc, 0,0,0);
        if (lh < 2){
            #pragma unroll
            for (int r=0;r<4;r++) outl[(lh*4+r)*OS + tt*16 + lr] = acc[r];
        }
    }
}

__device__ __forceinline__ void mm_gates_f(const _Float16* au, const _Float16* ah,
        const _Float16* __restrict__ Wcf, const _Float16* __restrict__ Whf,
        float* g1, float* g2, int w, int l){
    int lr = l&15, lh = l>>4;
    f16x8 Au[8], Ah[8];
    #pragma unroll
    for (int ks=0;ks<8;ks++){ Au[ks] = a16_ld8(au, lr, lh*8+ks*32);
                              Ah[ks] = a16_ld8(ah, lr, lh*8+ks*32); }
    #pragma unroll
    for (int tile=0; tile<6; ++tile){
        int tt = w*6 + tile;
        f32x4 a1 = {0.f,0.f,0.f,0.f}, a2 = {0.f,0.f,0.f,0.f};
        #pragma unroll
        for (int ks=0;ks<8;ks++)
            a1 = __builtin_amdgcn_mfma_f32_16x16x32_f16(Au[ks], wfrag_ld(Wcf,tt,ks,l), a1, 0,0,0);
        #pragma unroll
        for (int ks=0;ks<8;ks++)
            a2 = __builtin_amdgcn_mfma_f32_16x16x32_f16(Ah[ks], wfrag_ld(Whf,tt,ks,l), a2, 0,0,0);
        if (lh < 2){
            #pragma unroll
            for (int r=0;r<4;r++){
                int s = lh*4+r;
                g1[s*768 + tt*16 + lr] = a1[r];
                g2[s*768 + tt*16 + lr] = a2[r];
            }
        }
    }
}

// ---------------- init: slots + LN_sl -> qh via Wqk ----------------
__global__ __launch_bounds__(512) void k_init(const float* __restrict__ noise,
        const float* __restrict__ mu, const float* __restrict__ sg,
        const float* __restrict__ g_sl, const float* __restrict__ be_sl,
        const _Float16* __restrict__ Wqkf, const float* __restrict__ cq,
        float* __restrict__ slots, _Float16* __restrict__ qh16) {
    __shared__ __align__(16) _Float16 a16[16*256];
    __shared__ float g1[8*256];
    int t = threadIdx.x, w = t>>6, l = t&63, b = blockIdx.x;
    int col = l*4;
    float4 nz = *(const float4*)(noise + ((long)b*8+w)*256 + col);
    float4 muv = *(const float4*)(mu + col);
    float4 sgv = *(const float4*)(sg + col);
    float4 sl;
    sl.x = muv.x + __expf(sgv.x)*nz.x; sl.y = muv.y + __expf(sgv.y)*nz.y;
    sl.z = muv.z + __expf(sgv.z)*nz.z; sl.w = muv.w + __expf(sgv.w)*nz.w;
    *(float4*)(slots + ((long)b*8+w)*256 + col) = sl;
    float s1 = sl.x+sl.y+sl.z+sl.w;
    float s2 = sl.x*sl.x+sl.y*sl.y+sl.z*sl.z+sl.w*sl.w;
    #pragma unroll
    for (int m=1;m<64;m<<=1){ s1+=__shfl_xor(s1,m); s2+=__shfl_xor(s2,m); }
    float mean = s1*(1.0f/D_);
    float inv = rsqrtf(s2*(1.0f/D_) - mean*mean + EPSL);
    float4 gv = *(const float4*)(g_sl + col);
    float4 bb = *(const float4*)(be_sl + col);
    float4 sn;
    sn.x=(sl.x-mean)*inv*gv.x+bb.x; sn.y=(sl.y-mean)*inv*gv.y+bb.y;
    sn.z=(sl.z-mean)*inv*gv.z+bb.z; sn.w=(sl.w-mean)*inv*gv.w+bb.w;
    a16_st4(a16, w, col, sn);
    float4 z = {0.f,0.f,0.f,0.f};
    a16_st4(a16, 8+w, col, z);
    __syncthreads();
    mm_stage_f<2,256>(a16, Wqkf, g1, w, l);
    __syncthreads();
    for (int idx=t; idx<2048; idx+=512){
        int s = idx>>8, d = idx&255;
        qh16[((long)b*16+s)*D_ + d] = (_Float16)(g1[s*256+d] + cq[d]);
        qh16[((long)b*16+8+s)*D_ + d] = (_Float16)0.f;
    }
}

// ---------------- attn: SINGLE-buffer per-wave staging (R12-proven) ----------
__global__ __launch_bounds__(256) void k_attn(const _Float16* __restrict__ xn,
        const _Float16* __restrict__ qh16,
        _Float16* __restrict__ pacc, float* __restrict__ ppsum,
        float* __restrict__ pmax) {
    __shared__ __align__(16) char xt_raw[4*8192];    // 1 x 8 KB per wave; reused as accw
    __shared__ __align__(16) float pt_s[4][16][8];
    __shared__ float mw_s[4][8], psw_s[4][8];
    int t = threadIdx.x, w = t>>6, l = t&63, lr = l&15, lh = l>>4;
    int c = blockIdx.x, b = blockIdx.y;

    f16x8 A[8];
    const _Float16* qbase = qh16 + ((long)b*16 + lr)*D_ + lh*8;
    #pragma unroll
    for (int ks=0;ks<8;ks++) A[ks] = *(const f16x8*)(qbase + ks*32);
    asm volatile("s_waitcnt vmcnt(0)" ::: "memory");

    char* xw = xt_raw + w*8192;
    const char* xnb = (const char*)(xn + (long)b*N_*D_);
    int rlo = l>>5;
    int cb  = (l&31)*16;

    {   int n0 = c*512 + w*16;
        #pragma unroll
        for (int j=0;j<8;j++){
            int row = 2*j + rlo;
            const char* gp = xnb + (long)(n0+row)*512 + (cb ^ ((row&7)<<4));
            gload_lds16_nt(gp, xw + j*1024);
        }
    }

    float m8[8];
    #pragma unroll
    for (int s=0;s<8;s++) m8[s] = -1e30f;
    float acc[8][4] = {};
    float psr[4] = {0.f,0.f,0.f,0.f};
    float (*pt)[8] = pt_s[w];
    int fx = (lr&7)<<4;

    for (int sc=0; sc<8; ++sc){
        asm volatile("s_waitcnt vmcnt(0)" ::: "memory");
        __builtin_amdgcn_sched_barrier(0);

        f32x4 lacc = {0.f,0.f,0.f,0.f};
        #pragma unroll
        for (int ks=0;ks<8;ks++){
            f16x8 Bf = *(const f16x8*)(xw + lr*512 + ((lh*16 + ks*64) ^ fx));
            lacc = __builtin_amdgcn_mfma_f32_16x16x32_f16(A[ks], Bf, lacc, 0,0,0);
        }
        float tm[4];
        #pragma unroll
        for (int r=0;r<4;r++) tm[r] = lacc[r];
        #pragma unroll
        for (int m=1;m<16;m<<=1){
            #pragma unroll
            for (int r=0;r<4;r++) tm[r] = fmaxf(tm[r], __shfl_xor(tm[r], m));
        }
        float mN[8];
        #pragma unroll
        for (int r=0;r<4;r++){ mN[r] = __shfl(tm[r], lr); mN[4+r] = __shfl(tm[r], 16+lr); }
        float sc8[8];
        #pragma unroll
        for (int s=0;s<8;s++){
            float mn = fmaxf(m8[s], mN[s]);
            sc8[s] = __expf(m8[s] - mn);
            m8[s] = mn;
        }
        #pragma unroll
        for (int s=0;s<8;s++){
            acc[s][0]*=sc8[s]; acc[s][1]*=sc8[s]; acc[s][2]*=sc8[s]; acc[s][3]*=sc8[s];
        }
        if (lh < 2){
            float4 pv;
            #pragma unroll
            for (int r=0;r<4;r++){
                int s = lh*4+r;
                float p = __expf(lacc[r] - m8[s]);
                psr[r] = psr[r]*sc8[s] + p;
                ((float*)&pv)[r] = p;
            }
            *(float4*)&pt[lr][lh*4] = pv;
        }
        #pragma unroll 4
        for (int i=0;i<16;i++){
            float4 p0 = *(const float4*)&pt[i][0];
            float4 p1 = *(const float4*)&pt[i][4];
            f16x4 xv = *(const f16x4*)(xw + i*512 + ((l*8) ^ ((i&7)<<4)));
            float x0=(float)xv[0], x1=(float)xv[1], x2=(float)xv[2], x3=(float)xv[3];
            acc[0][0]+=p0.x*x0; acc[0][1]+=p0.x*x1; acc[0][2]+=p0.x*x2; acc[0][3]+=p0.x*x3;
            acc[1][0]+=p0.y*x0; acc[1][1]+=p0.y*x1; acc[1][2]+=p0.y*x2; acc[1][3]+=p0.y*x3;
            acc[2][0]+=p0.z*x0; acc[2][1]+=p0.z*x1; acc[2][2]+=p0.z*x2; acc[2][3]+=p0.z*x3;
            acc[3][0]+=p0.w*x0; acc[3][1]+=p0.w*x1; acc[3][2]+=p0.w*x2; acc[3][3]+=p0.w*x3;
            acc[4][0]+=p1.x*x0; acc[4][1]+=p1.x*x1; acc[4][2]+=p1.x*x2; acc[4][3]+=p1.x*x3;
            acc[5][0]+=p1.y*x0; acc[5][1]+=p1.y*x1; acc[5][2]+=p1.y*x2; acc[5][3]+=p1.y*x3;
            acc[6][0]+=p1.z*x0; acc[6][1]+=p1.z*x1; acc[6][2]+=p1.z*x2; acc[6][3]+=p1.z*x3;
            acc[7][0]+=p1.w*x0; acc[7][1]+=p1.w*x1; acc[7][2]+=p1.w*x2; acc[7][3]+=p1.w*x3;
        }
        if (sc < 7){
            asm volatile("s_waitcnt lgkmcnt(0)" ::: "memory");
            __builtin_amdgcn_sched_barrier(0);
            int n0n = c*512 + (sc+1)*64 + w*16;
            #pragma unroll
            for (int j=0;j<8;j++){
                int row = 2*j + rlo;
                const char* gp = xnb + (long)(n0n+row)*512 + (cb ^ ((row&7)<<4));
                gload_lds16_nt(gp, xw + j*1024);
            }
        }
    }
    #pragma unroll
    for (int m=1;m<16;m<<=1){
        #pragma unroll
        for (int r=0;r<4;r++) psr[r] += __shfl_xor(psr[r], m);
    }
    if (l == 0){
        #pragma unroll
        for (int s=0;s<8;s++) mw_s[w][s] = m8[s];
        #pragma unroll
        for (int r=0;r<4;r++) psw_s[w][r] = psr[r];
    }
    if (l == 16){
        #pragma unroll
        for (int r=0;r<4;r++) psw_s[w][4+r] = psr[r];
    }
    __syncthreads();
    float M8[8];
    #pragma unroll
    for (int s=0;s<8;s++)
        M8[s] = fmaxf(fmaxf(mw_s[0][s],mw_s[1][s]), fmaxf(mw_s[2][s],mw_s[3][s]));
    float* accw = (float*)xt_raw;   // [4 waves][8 s][256 d] = 32 KB
    #pragma unroll
    for (int s=0;s<8;s++){
        float wsc = __expf(m8[s] - M8[s]);
        float4 v;
        v.x=acc[s][0]*wsc; v.y=acc[s][1]*wsc; v.z=acc[s][2]*wsc; v.w=acc[s][3]*wsc;
        *(float4*)&accw[((w*8+s)<<8) + l*4] = v;
    }
    __syncthreads();
    for (int pair=t; pair<2048; pair+=256){
        int s = pair>>8, d = pair&255;
        float v = accw[(s<<8)+d] + accw[((8+s)<<8)+d] + accw[((16+s)<<8)+d] + accw[((24+s)<<8)+d];
        pacc[(((long)b*8 + c)*8 + s)*D_ + d] = (_Float16)v;
    }
    if (t < 8){
        float ps = 0.f;
        #pragma unroll
        for (int w2=0;w2<4;w2++) ps += __expf(mw_s[w2][t]-M8[t]) * psw_s[w2][t];
        ppsum[((long)b*8+c)*8 + t] = ps;
        pmax [((long)b*8+c)*8 + t] = M8[t];
    }
}

// ---------------- tail: 128 blocks, 4 slots each ----------------
__global__ __launch_bounds__(512) void k_tail(
    const _Float16* __restrict__ pacc, const float* __restrict__ ppsum,
    const float* __restrict__ pmax, const float* __restrict__ slots,
    const _Float16* __restrict__ Wcf, const float* __restrict__ bc,
    const _Float16* __restrict__ Whhf, const float* __restrict__ bhh,
    const _Float16* __restrict__ W1f, const float* __restrict__ b1,
    const _Float16* __restrict__ W2f, const float* __restrict__ b2,
    const float* __restrict__ gm, const float* __restrict__ bem,
    const float* __restrict__ g_sl, const float* __restrict__ be_sl,
    const _Float16* __restrict__ Wqkf, const float* __restrict__ cq,
    float* __restrict__ out, _Float16* __restrict__ qh16, int last) {
    int t = threadIdx.x, w = t>>6, l = t&63;
    int bid = blockIdx.x;
    int b = bid >> 1, h = bid & 1;       // h: which half of the 8 slots
    __shared__ float hb[4][256], hn[4][256];
    __shared__ float g1[8*768], g2[8*768];
    __shared__ __align__(16) _Float16 a16a[16*256], a16b[16*256];
    __shared__ float pss[4];
    __shared__ float wcs[4][8];

    if (t < 4){
        int gs = h*4 + t;
        float pm[8]; float M = -1e30f;
        #pragma unroll
        for (int c=0;c<8;c++){ pm[c] = pmax[((long)b*8+c)*8+gs]; M = fmaxf(M, pm[c]); }
        float ps = 0.f;
        #pragma unroll
        for (int c=0;c<8;c++){
            float wc = __expf(pm[c]-M);
            wcs[t][c] = wc;
            ps += wc*ppsum[((long)b*8+c)*8+gs];
        }
        pss[t] = ps;
    }
    __syncthreads();
    for (int idx=t; idx<1024; idx+=512){
        int s = idx>>8, d = idx&255;     // s: 0..3 local
        int gs = h*4 + s;
        float v = 0.f;
        #pragma unroll
        for (int c=0;c<8;c++) v += wcs[s][c]*(float)pacc[(((long)b*8+c)*8+gs)*D_ + d];
        float axv = v / pss[s];
        float hbv = slots[((long)b*8+gs)*D_ + d];
        hb[s][d] = hbv;
        a16_st2(a16a, s, d, (_Float16)axv);
        a16_st2(a16b, s, d, (_Float16)hbv);
    }
    {   float4 z = {0.f,0.f,0.f,0.f};
        a16_st4(a16a, 4+w, l*4, z);      // rows 4..11
        a16_st4(a16b, 4+w, l*4, z);
        if (w < 4){                       // rows 12..15
            a16_st4(a16a, 12+w, l*4, z);
            a16_st4(a16b, 12+w, l*4, z);
        }
    }
    __syncthreads();
    mm_gates_f(a16a, a16b, Wcf, Whhf, g1, g2, w, l);
    __syncthreads();
    if (w < 4){
        int d0 = l*4;
        float hn4[4];
        #pragma unroll
        for (int i=0;i<4;i++){
            int d = d0+i;
            float r = 1.f/(1.f+__expf(-(g1[w*768+d]     + bc[d]     + g2[w*768+d]     + bhh[d])));
            float z = 1.f/(1.f+__expf(-(g1[w*768+256+d] + bc[256+d] + g2[w*768+256+d] + bhh[256+d])));
            float gg = g1[w*768+512+d] + bc[512+d] + r*(g2[w*768+512+d] + bhh[512+d]);
            float e2 = __expf(2.f*gg);
            float nn = 1.f - 2.f/(e2+1.f);
            hn4[i] = (1.f-z)*nn + z*hb[w][d];
            hn[w][d] = hn4[i];
        }
        float s1 = hn4[0]+hn4[1]+hn4[2]+hn4[3];
        float s2 = hn4[0]*hn4[0]+hn4[1]*hn4[1]+hn4[2]*hn4[2]+hn4[3]*hn4[3];
        #pragma unroll
        for (int m=1;m<64;m<<=1){ s1+=__shfl_xor(s1,m); s2+=__shfl_xor(s2,m); }
        float mean = s1*(1.0f/D_);
        float inv = rsqrtf(s2*(1.0f/D_) - mean*mean + EPSL);
        float4 gv = *(const float4*)(gm + d0);
        float4 bb = *(const float4*)(bem + d0);
        float4 v;
        v.x=(hn4[0]-mean)*inv*gv.x+bb.x; v.y=(hn4[1]-mean)*inv*gv.y+bb.y;
        v.z=(hn4[2]-mean)*inv*gv.z+bb.z; v.w=(hn4[3]-mean)*inv*gv.w+bb.w;
        a16_st4(a16a, w, d0, v);
    }
    __syncthreads();
    mm_stage_f<2,256>(a16a, W1f, g1, w, l);
    __syncthreads();
    if (w < 4){
        int d0 = l*4;
        float4 v = *(const float4*)&g1[w*256+d0];
        float4 bb = *(const float4*)(b1 + d0);
        v.x=fmaxf(v.x+bb.x,0.f); v.y=fmaxf(v.y+bb.y,0.f);
        v.z=fmaxf(v.z+bb.z,0.f); v.w=fmaxf(v.w+bb.w,0.f);
        a16_st4(a16b, w, d0, v);
    }
    __syncthreads();
    mm_stage_f<2,256>(a16b, W2f, g2, w, l);
    __syncthreads();
    if (w < 4){
        int d0 = l*4;
        float4 bb = *(const float4*)(b2 + d0);
        float4 o4;
        o4.x = hn[w][d0]   + g2[w*256+d0]   + bb.x;
        o4.y = hn[w][d0+1] + g2[w*256+d0+1] + bb.y;
        o4.z = hn[w][d0+2] + g2[w*256+d0+2] + bb.z;
        o4.w = hn[w][d0+3] + g2[w*256+d0+3] + bb.w;
        *(float4*)(out + ((long)b*8 + h*4 + w)*D_ + d0) = o4;
        if (!last){
            float s1 = o4.x+o4.y+o4.z+o4.w;
            float s2 = o4.x*o4.x+o4.y*o4.y+o4.z*o4.z+o4.w*o4.w;
            #pragma unroll
            for (int m=1;m<64;m<<=1){ s1+=__shfl_xor(s1,m); s2+=__shfl_xor(s2,m); }
            float mean = s1*(1.0f/D_);
            float inv = rsqrtf(s2*(1.0f/D_) - mean*mean + EPSL);
            float4 gv = *(const float4*)(g_sl + d0);
            float4 be = *(const float4*)(be_sl + d0);
            float4 v;
            v.x=(o4.x-mean)*inv*gv.x+be.x; v.y=(o4.y-mean)*inv*gv.y+be.y;
            v.z=(o4.z-mean)*inv*gv.z+be.z; v.w=(o4.w-mean)*inv*gv.w+be.w;
            a16_st4(a16a, w, d0, v);
        }
    }
    if (last) return;
    __syncthreads();
    mm_stage_f<2,256>(a16a, Wqkf, g1, w, l);
    __syncthreads();
    for (int idx=t; idx<1024; idx+=512){
        int s = idx>>8, d = idx&255;
        qh16[((long)b*16 + h*4 + s)*D_ + d] = (_Float16)(g1[s*256+d] + cq[d]);
    }
}

extern "C" void kernel_launch(void* const* d_in, const int* in_sizes, int n_in,
                              void* d_out, int out_size, void* d_ws, size_t ws_size,
                              hipStream_t stream) {
    const float* x     = (const float*)d_in[0];
    const float* noise = (const float*)d_in[1];
    const float* mu    = (const float*)d_in[2];
    const float* sg    = (const float*)d_in[3];
    const float* Wq    = (const float*)d_in[4];
    const float* bq    = (const float*)d_in[5];
    const float* Wk    = (const float*)d_in[6];
    // d_in[7] = bk: softmax-invariant, unused
    const float* Wv    = (const float*)d_in[8];
    const float* bv    = (const float*)d_in[9];
    const float* Wih   = (const float*)d_in[10];
    const float* bih   = (const float*)d_in[11];
    const float* Whh   = (const float*)d_in[12];
    const float* bhh   = (const float*)d_in[13];
    const float* W1    = (const float*)d_in[14];
    const float* b1    = (const float*)d_in[15];
    const float* W2    = (const float*)d_in[16];
    const float* b2    = (const float*)d_in[17];
    const float* g_in  = (const float*)d_in[18];
    const float* be_in = (const float*)d_in[19];
    const float* g_sl  = (const float*)d_in[20];
    const float* be_sl = (const float*)d_in[21];
    const float* g_mlp = (const float*)d_in[22];
    const float* be_mlp= (const float*)d_in[23];

    char* ws = (char*)d_ws;
    _Float16* xn16  = (_Float16*)(ws);                   // 134217728 B
    _Float16* qh16  = (_Float16*)(ws + 134217728);       //    524288 B
    float*    slots = (float*)   (ws + 134742016);       //    524288 B
    _Float16* pacc  = (_Float16*)(ws + 135266304);       //   2097152 B
    float*    ppsum = (float*)   (ws + 152043520);       //     16384 B
    float*    pmax  = (float*)   (ws + 152059904);       //     16384 B
    _Float16* w16f  = (_Float16*)(ws + 152076288);       //   1179648 B
    float*    bc    = (float*)   (ws + 153255936);       //      3072 B
    float*    cq    = (float*)   (ws + 153259008);       //      1024 B

    _Float16* Wcf  = w16f;             // 768x256 frag
    _Float16* Whhf = w16f + 196608;    // 768x256 frag
    _Float16* W1f  = w16f + 393216;    // 256x256 frag
    _Float16* W2f  = w16f + 458752;    // 256x256 frag
    _Float16* Wqkf = w16f + 524288;    // 256x256 frag

    hipLaunchKernelGGL(k_wpre, dim3(1536), dim3(256), 0, stream,
                       Whh, W1, W2, Whhf, W1f, W2f,
                       Wih, Wv, Wq, Wk, bih, bv, bq, Wcf, Wqkf, bc, cq);
    hipLaunchKernelGGL(k_ln_x, dim3(32768), dim3(256), 0, stream, x, g_in, be_in, xn16);
    hipLaunchKernelGGL(k_init, dim3(64), dim3(512), 0, stream,
                       noise, mu, sg, g_sl, be_sl, Wqkf, cq, slots, qh16);
    for (int it = 0; it < 3; it++){
        hipLaunchKernelGGL(k_attn, dim3(8,64), dim3(256), 0, stream,
                           xn16, qh16, pacc, ppsum, pmax);
        float* dst = (it==2) ? (float*)d_out : slots;
        hipLaunchKernelGGL(k_tail, dim3(128), dim3(512), 0, stream,
                           pacc, ppsum, pmax, slots,
                           Wcf, bc, Whhf, bhh, W1f, b1, W2f, b2,
                           g_mlp, be_mlp, g_sl, be_sl, Wqkf, cq,
                           dst, qh16, (it==2) ? 1 : 0);
    }
}